// Round 7
// baseline (218.000 us; speedup 1.0000x reference)
//
#include <hip/hip_runtime.h>
#include <math.h>

#define EPSF 1e-6f
#define MAX_ACOSH_ARGF 1e6f
#define MAX_DISTF 50.0f
#define TINYF 1e-15f

typedef float f4v __attribute__((ext_vector_type(4)));
typedef float f2v __attribute__((ext_vector_type(2)));

constexpr int TENS = 16 * 512 * 36;   // per-tensor floats (rows padded to 36)

__device__ __forceinline__ float facosh(float a) {
    // a >= 1+EPS guaranteed by clamp; (a-1)(a+1) avoids a*a-1 cancellation
    return __logf(a + sqrtf((a - 1.0f) * (a + 1.0f)));
}
__device__ __forceinline__ float bcast(float x) {
    return __int_as_float(__builtin_amdgcn_readfirstlane(__float_as_int(x)));
}
template<int C> __device__ __forceinline__ float dpp_add(float x) {
    int t = __builtin_amdgcn_update_dpp(0, __float_as_int(x), C, 0xf, 0xf, false);
    return x + __int_as_float(t);
}
// sum across 64 lanes via DPP scans (pure VALU, no LDS); lane 63 holds total
__device__ __forceinline__ float redsum64(float x) {
    x = dpp_add<0x111>(x);   // row_shr:1
    x = dpp_add<0x112>(x);   // row_shr:2
    x = dpp_add<0x114>(x);   // row_shr:4
    x = dpp_add<0x118>(x);   // row_shr:8  -> lane15 of each row16 = row sum
    x = dpp_add<0x142>(x);   // row_bcast:15 -> lane31/63 = 32-half sums
    x = dpp_add<0x143>(x);   // row_bcast:31 -> lane63 = total
    return x;
}

// ---------------- Kernel 1: QKV GEMM (LDS-free, 4-deep prefetch) + lift -------
// 1536 waves: wave = 4 bt-rows x 128 cols. A rows broadcast f4, B coalesced f2.
__global__ __launch_bounds__(64) void qkv_kernel(
    const float* __restrict__ x,
    const float* __restrict__ Wq, const float* __restrict__ bq,
    const float* __restrict__ Wk, const float* __restrict__ bk,
    const float* __restrict__ Wv, const float* __restrict__ bv,
    float* __restrict__ Q, float* __restrict__ K, float* __restrict__ V)
{
    const int lane = threadIdx.x;
    const int gw   = blockIdx.x;               // 0..1535
    const int ct   = gw % 6;
    const int mt   = gw / 6;                   // 0..255
    const int m0   = mt * 4;
    const int tsel = ct >> 1;
    const int n0   = (ct & 1) * 128;
    const float* W    = (tsel == 0) ? Wq : (tsel == 1) ? Wk : Wv;
    const float* bias = (tsel == 0) ? bq : (tsel == 1) ? bk : bv;
    float* OUT        = (tsel == 0) ? Q  : (tsel == 1) ? K  : V;
    const int c0 = n0 + lane * 2;
    const float* xb = x + m0 * 512;

    float acc[4][2];
    {
        const float b0 = bias[c0], b1 = bias[c0 + 1];
        #pragma unroll
        for (int r = 0; r < 4; ++r) { acc[r][0] = b0; acc[r][1] = b1; }
    }

    f4v a[4][4][2];   // [buf][row][half]
    f2v b[4][8];      // [buf][j]

#define LDQ(B, KB)                                                      \
    { _Pragma("unroll") for (int r = 0; r < 4; ++r) {                   \
          a[B][r][0] = *(const f4v*)(xb + r * 512 + (KB));              \
          a[B][r][1] = *(const f4v*)(xb + r * 512 + (KB) + 4); }        \
      _Pragma("unroll") for (int j = 0; j < 8; ++j)                     \
          b[B][j] = *(const f2v*)(W + ((KB) + j) * 256 + c0); }
#define STQ(B)                                                          \
    { _Pragma("unroll") for (int j = 0; j < 8; ++j) {                   \
        _Pragma("unroll") for (int r = 0; r < 4; ++r) {                 \
            const float av = a[B][r][j >> 2][j & 3];                    \
            acc[r][0] = fmaf(av, b[B][j][0], acc[r][0]);                \
            acc[r][1] = fmaf(av, b[B][j][1], acc[r][1]); } } }

    LDQ(0, 0) LDQ(1, 8) LDQ(2, 16) LDQ(3, 24)
    for (int kb = 0; kb < 480; kb += 32) {
        STQ(0) LDQ(0, kb + 32)
        STQ(1) LDQ(1, kb + 40)
        STQ(2) LDQ(2, kb + 48)
        STQ(3) LDQ(3, kb + 56)
    }
    STQ(0) STQ(1) STQ(2) STQ(3)
#undef LDQ
#undef STQ

    // fused lift: 16-lane subgroup = one head's 32 cols; row-major [bh][t][36]
    const int h   = c0 >> 5;
    const int cin = c0 & 31;
    #pragma unroll
    for (int r = 0; r < 4; ++r) {
        const float e0 = acc[r][0], e1 = acc[r][1];
        float n2 = fmaf(e0, e0, e1 * e1);
        #pragma unroll
        for (int msk = 1; msk < 16; msk <<= 1) n2 += __shfl_xor(n2, msk, 64);
        n2 = fmaxf(n2, TINYF);
        const float vn = sqrtf(n2);
        const float ch = coshf(vn);
        const float sh = sinhf(vn) / fmaxf(vn, TINYF);
        const float xx = fmaf(sh * sh, n2, -ch * ch);      // mink(y,y) ~ -1
        const float scale = sqrtf(fmaxf(fabsf(xx), TINYF));
        const float fs = sh / scale;
        const int bt = m0 + r, bb = bt >> 9, t = bt & 511;
        float* rp = OUT + ((bb * 8 + h) * 512 + t) * 36;
        rp[1 + cin] = fs * e0;
        rp[2 + cin] = fs * e1;
        if (cin == 0) {
            rp[0] = fabsf(ch / scale);
            rp[33] = 0.0f; rp[34] = 0.0f; rp[35] = 0.0f;
        }
    }
}

// ---------------- Kernel 2: attention + Karcher step + log-map ----------------
// 512 blocks x 512 thr (8 waves, 2 blocks/CU). Wave = 2 q (SGPR via bcast).
// K/V LDS-staged in 64-row double-buffered chunks; lane = row (64 unique rows
// per ds_read -> full LDS efficiency). No softmax max-tracking (scores <= 0).
// Cross-lane merge via DPP adds (VALU only); lane 63 runs the epilogue.
__global__ __launch_bounds__(512, 4) void attn_kernel(
    const float* __restrict__ Qg, const float* __restrict__ Kg,
    const float* __restrict__ Vg, float* __restrict__ ZT)
{
    __shared__ f4v skv[2][1152];   // [buf][ K rows 576 f4 | V rows 576 f4 ]
    __shared__ f4v sQ4[144];       // 16 q rows x 9 f4

    const int tid = threadIdx.x;
    const int blk = blockIdx.x;            // 512
    const int bh  = blk >> 5;              // 0..15
    const int q0t = (blk & 31) * 16;
    const int wid = __builtin_amdgcn_readfirstlane(tid >> 6);
    const int lane = tid & 63;

    const f4v* K4 = (const f4v*)(Kg + bh * 512 * 36);
    const f4v* V4 = (const f4v*)(Vg + bh * 512 * 36);

    // per-thread staging map: 1152 f4 per chunk over 512 thr (+128 extra)
    const f4v* s0 = K4 + tid;                                    // 0..511 (K)
    const f4v* s1 = (tid < 64) ? (K4 + 512 + tid) : (V4 + (tid - 64));
    const f4v* s2 = V4 + 448 + tid;                              // tid<128
    const int d0 = tid, d1 = tid + 512, d2 = tid + 1024;

    // stage chunk 0 + Q
    skv[0][d0] = s0[0];
    skv[0][d1] = s1[0];
    if (tid < 128) skv[0][d2] = s2[0];
    if (tid < 144) sQ4[tid] = ((const f4v*)(Qg + (bh * 512 + q0t) * 36))[tid];
    __syncthreads();

    // two q rows per wave -> SGPRs (negated spatial comps; pads are 0)
    float qn0[36], qn1[36];
    {
        const float* qs = (const float*)sQ4;
        #pragma unroll
        for (int a2 = 0; a2 < 36; ++a2) {
            const float v0 = qs[(2 * wid) * 36 + a2];
            const float v1 = qs[(2 * wid + 1) * 36 + a2];
            qn0[a2] = bcast(a2 ? -v0 : v0);
            qn1[a2] = bcast(a2 ? -v1 : v1);
        }
    }

    float l0 = 0.0f, l1 = 0.0f;
    float ac0[33], ac1[33];
    #pragma unroll
    for (int a2 = 0; a2 < 33; ++a2) { ac0[a2] = 0.0f; ac1[a2] = 0.0f; }

    for (int c = 0; c < 8; ++c) {
        f4v p0, p1, p2;
        const bool have = (c < 7);
        if (have) {                          // issue next-chunk loads early
            p0 = s0[(c + 1) * 576];
            p1 = s1[(c + 1) * 576];
            if (tid < 128) p2 = s2[(c + 1) * 576];
        }
        const f4v* buf = skv[c & 1];
        const f4v* kr = buf + lane * 9;      // K row = lane (64 unique rows)
        const f4v* vr = buf + 576 + lane * 9;

        // K phase (streamed, small register window)
        float x10 = 0.f, x11 = 0.f, x20 = 0.f, x21 = 0.f;
        #pragma unroll
        for (int j = 0; j < 9; ++j) {
            const f4v kv = kr[j];
            x10 = fmaf(qn0[4 * j],     kv[0], x10);
            x11 = fmaf(qn0[4 * j + 1], kv[1], x11);
            x10 = fmaf(qn0[4 * j + 2], kv[2], x10);
            x11 = fmaf(qn0[4 * j + 3], kv[3], x11);
            x20 = fmaf(qn1[4 * j],     kv[0], x20);
            x21 = fmaf(qn1[4 * j + 1], kv[1], x21);
            x20 = fmaf(qn1[4 * j + 2], kv[2], x20);
            x21 = fmaf(qn1[4 * j + 3], kv[3], x21);
        }
        const float a1q0 = x10 + x11, a1q1 = x20 + x21;

        // stage write (frees p regs before V phase peak)
        if (have) {
            f4v* w = skv[(c + 1) & 1];
            w[d0] = p0; w[d1] = p1;
            if (tid < 128) w[d2] = p2;
        }

        // V phase (row held in registers for dot + accumulate)
        f4v vf[9];
        #pragma unroll
        for (int j = 0; j < 9; ++j) vf[j] = vr[j];
        float y10 = 0.f, y11 = 0.f, y20 = 0.f, y21 = 0.f;
        #pragma unroll
        for (int j = 0; j < 9; ++j) {
            y10 = fmaf(qn0[4 * j],     vf[j][0], y10);
            y11 = fmaf(qn0[4 * j + 1], vf[j][1], y11);
            y10 = fmaf(qn0[4 * j + 2], vf[j][2], y10);
            y11 = fmaf(qn0[4 * j + 3], vf[j][3], y11);
            y20 = fmaf(qn1[4 * j],     vf[j][0], y20);
            y21 = fmaf(qn1[4 * j + 1], vf[j][1], y21);
            y20 = fmaf(qn1[4 * j + 2], vf[j][2], y20);
            y21 = fmaf(qn1[4 * j + 3], vf[j][3], y21);
        }
        const float a2q0 = y10 + y11, a2q1 = y20 + y21;

        // weights (no max-subtraction: scores <= 0, exp in [0,1])
        {
            const float a1c = fminf(fmaxf(a1q0, 1.0f + EPSF), MAX_ACOSH_ARGF);
            const float dd  = fminf(facosh(a1c), MAX_DISTF);
            const float e   = __expf(-dd * dd);
            const float a2c = fminf(fmaxf(a2q0, 1.0f + EPSF), MAX_ACOSH_ARGF);
            const float w0  = e * facosh(a2c);
            l0 += e;
            #pragma unroll
            for (int a2 = 0; a2 < 33; ++a2)
                ac0[a2] = fmaf(w0, vf[a2 >> 2][a2 & 3], ac0[a2]);
        }
        {
            const float a1c = fminf(fmaxf(a1q1, 1.0f + EPSF), MAX_ACOSH_ARGF);
            const float dd  = fminf(facosh(a1c), MAX_DISTF);
            const float e   = __expf(-dd * dd);
            const float a2c = fminf(fmaxf(a2q1, 1.0f + EPSF), MAX_ACOSH_ARGF);
            const float w1  = e * facosh(a2c);
            l1 += e;
            #pragma unroll
            for (int a2 = 0; a2 < 33; ++a2)
                ac1[a2] = fmaf(w1, vf[a2 >> 2][a2 & 3], ac1[a2]);
        }
        __syncthreads();
    }

    // ---- merge across 64 lanes (pure VALU DPP; totals land on lane 63) ----
    const float lw0 = redsum64(l0);
    const float lw1 = redsum64(l1);
    #pragma unroll
    for (int a2 = 0; a2 < 33; ++a2) {
        ac0[a2] = redsum64(ac0[a2]);
        ac1[a2] = redsum64(ac1[a2]);
    }

    if (lane == 63) {
        const int b = bh >> 3, h = bh & 7;
        #pragma unroll
        for (int q = 0; q < 2; ++q) {
            float (&ac)[33] = q ? ac1 : ac0;
            const float (&qn)[36] = q ? qn1 : qn0;
            const float lw = q ? lw1 : lw0;
            // fold scalar Q-side: step ∝ Σw·v + (Σw·a2)·q ; Σw·a2 = <qn, ac>
            float sw = 0.0f;
            #pragma unroll
            for (int a2 = 0; a2 < 33; ++a2) sw = fmaf(qn[a2], ac[a2], sw);
            const float un_c  = 3.1622776601683794e-8f;   // sqrt(1e-15)
            const float inv_un = (1.0f / lw) / un_c;
            ac[0] = fmaf(sw, qn[0], ac[0]) * inv_un;
            #pragma unroll
            for (int a2 = 1; a2 < 33; ++a2) ac[a2] = fmaf(-sw, qn[a2], ac[a2]) * inv_un;

            float mk = -ac[0] * ac[0];
            #pragma unroll
            for (int a2 = 1; a2 < 33; ++a2) mk = fmaf(ac[a2], ac[a2], mk);
            const float snorm = sqrtf(fmaxf(mk, TINYF));
            const float fac   = fminf(snorm, 20.0f) / (snorm + 1e-9f);
            #pragma unroll
            for (int a2 = 0; a2 < 33; ++a2) ac[a2] *= fac;

            float mk2 = -ac[0] * ac[0];
            #pragma unroll
            for (int a2 = 1; a2 < 33; ++a2) mk2 = fmaf(ac[a2], ac[a2], mk2);
            const float vn  = sqrtf(fmaxf(mk2, TINYF));
            const float ch  = coshf(vn);
            const float shr = sinhf(vn) / fmaxf(vn, TINYF);
            ac[0] = fmaf(ch, qn[0], shr * ac[0]);
            #pragma unroll
            for (int a2 = 1; a2 < 33; ++a2) ac[a2] = fmaf(-ch, qn[a2], shr * ac[a2]);

            float xx = -ac[0] * ac[0];
            #pragma unroll
            for (int a2 = 1; a2 < 33; ++a2) xx = fmaf(ac[a2], ac[a2], xx);
            const float scale = sqrtf(fmaxf(fabsf(xx), TINYF));

            const float Y0  = fabsf(ac[0] / scale);
            const float al3 = fminf(fmaxf(Y0, 1.0f + EPSF), MAX_ACOSH_ARGF);
            const float d3  = acoshf(al3);
            const float f3  = d3 / un_c;

            const int qi = q0t + 2 * wid + q;
            float* zp = ZT + (b * 512 + qi) * 264 + h * 33;
            zp[0] = f3 * (Y0 + al3);
            const float fsc = f3 / scale;
            #pragma unroll
            for (int a2 = 1; a2 < 33; ++a2) zp[a2] = fsc * ac[a2];
        }
    }
}

// ---------------- Kernel 3: Z = Z_tan @ Wo + bo (LDS-free, 4-deep prefetch) ---
__global__ __launch_bounds__(64) void out_kernel(
    const float* __restrict__ ZT, const float* __restrict__ Wo,
    const float* __restrict__ bo, float* __restrict__ out)
{
    const int lane = threadIdx.x;
    const int gw   = blockIdx.x;               // 0..1023
    const int mt   = gw >> 2;
    const int m0   = mt * 4;
    const int n0   = (gw & 3) * 128;
    const int c0   = n0 + lane * 2;
    const float* zb = ZT + m0 * 264;

    float acc[4][2];
    {
        const float b0 = bo[c0], b1 = bo[c0 + 1];
        #pragma unroll
        for (int r = 0; r < 4; ++r) { acc[r][0] = b0; acc[r][1] = b1; }
    }

    f4v a[4][4][2];
    f2v b[4][8];

#define LDO(B, KB)                                                      \
    { _Pragma("unroll") for (int r = 0; r < 4; ++r) {                   \
          a[B][r][0] = *(const f4v*)(zb + r * 264 + (KB));              \
          a[B][r][1] = *(const f4v*)(zb + r * 264 + (KB) + 4); }        \
      _Pragma("unroll") for (int j = 0; j < 8; ++j)                     \
          b[B][j] = *(const f2v*)(Wo + ((KB) + j) * 512 + c0); }
#define STO(B)                                                          \
    { _Pragma("unroll") for (int j = 0; j < 8; ++j) {                   \
        _Pragma("unroll") for (int r = 0; r < 4; ++r) {                 \
            const float av = a[B][r][j >> 2][j & 3];                    \
            acc[r][0] = fmaf(av, b[B][j][0], acc[r][0]);                \
            acc[r][1] = fmaf(av, b[B][j][1], acc[r][1]); } } }

    LDO(0, 0) LDO(1, 8) LDO(2, 16) LDO(3, 24)
    for (int kb = 0; kb < 224; kb += 32) {
        STO(0) LDO(0, kb + 32)
        STO(1) LDO(1, kb + 40)
        STO(2) LDO(2, kb + 48)
        STO(3) LDO(3, kb + 56)
    }
    // buffers now hold k = 224, 232, 240, 248; tail block 256..263
    STO(0) LDO(0, 256)
    STO(1) STO(2) STO(3)
    STO(0)
#undef LDO
#undef STO

    #pragma unroll
    for (int r = 0; r < 4; ++r)
        *(f2v*)(out + (m0 + r) * 512 + c0) = f2v{acc[r][0], acc[r][1]};
}

extern "C" void kernel_launch(void* const* d_in, const int* in_sizes, int n_in,
                              void* d_out, int out_size, void* d_ws, size_t ws_size,
                              hipStream_t stream) {
    const float* x  = (const float*)d_in[0];
    const float* Wq = (const float*)d_in[1];
    const float* bq = (const float*)d_in[2];
    const float* Wk = (const float*)d_in[3];
    const float* bk = (const float*)d_in[4];
    const float* Wv = (const float*)d_in[5];
    const float* bv = (const float*)d_in[6];
    const float* Wo = (const float*)d_in[7];
    const float* bo = (const float*)d_in[8];
    float* out = (float*)d_out;
    float* ws  = (float*)d_ws;

    float* Q   = ws;
    float* K   = ws + TENS;
    float* V   = ws + 2 * TENS;
    float* ZTp = ws + 3 * TENS;

    qkv_kernel<<<1536, 64, 0, stream>>>(x, Wq, bq, Wk, bk, Wv, bv, Q, K, V);
    attn_kernel<<<512, 512, 0, stream>>>(Q, K, V, ZTp);
    out_kernel<<<1024, 64, 0, stream>>>(ZTp, Wo, bo, out);
}